// Round 11
// baseline (120.314 us; speedup 1.0000x reference)
//
#include <hip/hip_runtime.h>
#include <hip/hip_bf16.h>

#define BS 8
#define SEQ 512
#define DKDIM 2048

using bf16x8 = __attribute__((ext_vector_type(8))) __bf16;
using f32x4  = __attribute__((ext_vector_type(4))) float;

__device__ __forceinline__ unsigned short f2bf(float f) {
    unsigned int u = __builtin_bit_cast(unsigned int, f);
    u += 0x7FFFu + ((u >> 16) & 1u);
    return (unsigned short)(u >> 16);
}

__device__ __forceinline__ void gload_lds16(const unsigned short* g, unsigned short* l) {
    __builtin_amdgcn_global_load_lds(
        (const __attribute__((address_space(1))) unsigned int*)g,
        (__attribute__((address_space(3))) unsigned int*)l, 16, 0, 0);
}

#define PH_BARRIER() asm volatile("s_barrier" ::: "memory")

// ---------------------------------------------------------------------------
// Transpose+convert: in [SEQ][DK] f32 (per batch) -> out [DK][SEQ] bf16
// ---------------------------------------------------------------------------
__global__ __launch_bounds__(256) void transpose_conv_kernel(
    const float* __restrict__ q, const float* __restrict__ k,
    unsigned short* __restrict__ qT, unsigned short* __restrict__ kT)
{
    int z = blockIdx.z;
    const float* in = (z < BS) ? q : k;
    unsigned short* out = (z < BS) ? qT : kT;
    int b = z & (BS - 1);
    in  += (size_t)b * SEQ * DKDIM;
    out += (size_t)b * DKDIM * SEQ;
    int s0 = blockIdx.y * 64;
    int d0 = blockIdx.x * 64;
    __shared__ unsigned short tile[64][66];
    int t = threadIdx.x;
    int tr  = t >> 4;
    int tc4 = (t & 15) * 4;
    #pragma unroll
    for (int p = 0; p < 4; ++p) {
        int s = p * 16 + tr;
        float4 v4 = *reinterpret_cast<const float4*>(&in[(size_t)(s0 + s) * DKDIM + d0 + tc4]);
        tile[s][tc4 + 0] = f2bf(v4.x);
        tile[s][tc4 + 1] = f2bf(v4.y);
        tile[s][tc4 + 2] = f2bf(v4.z);
        tile[s][tc4 + 3] = f2bf(v4.w);
    }
    __syncthreads();
    #pragma unroll
    for (int p = 0; p < 4; ++p) {
        int d = p * 16 + tr;
        ushort4 o;
        o.x = tile[tc4 + 0][d];
        o.y = tile[tc4 + 1][d];
        o.z = tile[tc4 + 2][d];
        o.w = tile[tc4 + 3][d];
        *reinterpret_cast<ushort4*>(&out[(size_t)(d0 + d) * SEQ + s0 + tc4]) = o;
    }
}

// ---------------------------------------------------------------------------
// GEMM1 (BK=32, 3 blocks/CU, 2-PHASE): E = exp(scale*(qT kT^T)) + partials.
// BM=BN=128, BK=32, NT=16, 4 waves (2Mx2N), wave tile 64x64, acc[4][4].
// LDS 32KB, launch_bounds(256,3) => 3 blocks/CU (r10-verified, 35% occ).
// ROUND-11 CHANGES vs r10:
//  (a) swizzle fixed: chunk ^= (row>>1)&3 (r10's row&3 repeated bank-starts
//      within each 8-lane octet -> 4.2e6 conflicts; this one covers banks
//      {0,4,..28} exactly per octet -> conflict-free, enumerated).
//  (b) 2 phases/k-tile (4 barriers, 8 MFMA/phase — r10's 4-MFMA phases were
//      barrier-dominated):
//      phA: rd alo,blo,bhi (6 b128); stage Ahi,Bhi(t+1)->buf^1 (disjoint
//           buffer from this phase's reads); BAR lgk0 prio1 q00+q01 prio0 BAR
//      phB: rd ahi (2 b128); stage Alo,Blo(t+2)->buf (disjoint halves from
//           ahi: row&32 split); BAR lgk0 prio1 q11+q10 prio0 vmcnt BAR
//      Liveness: each staged target's last reader phase closed by lgk0+BAR
//      before the staging phase. Tile-end vmcnt(2): outstanding = phB's 2
//      loads of t+2 => {Ahi,Bhi}(t+1) landed; {Alo,Blo}(t+1) older => landed.
//      vmcnt(0) at NT-2. Prologue: t0 all + t1 {Alo,Blo} = 6 loads, vmcnt(2).
// Grid 2048, bz=wg&7 => XCD i owns batch i.
// ---------------------------------------------------------------------------
__global__ __launch_bounds__(256, 3) void gemm1_qk_exp(
    const unsigned short* __restrict__ A,   // qT [b][2048][512]
    const unsigned short* __restrict__ B,   // kT [b][2048][512]
    unsigned short* __restrict__ E,         // [b][2048][2048]
    float* __restrict__ rpart,              // [32][BS][2048]
    float scale)
{
    constexpr int K = SEQ;      // 512
    constexpr int N = DKDIM;    // 2048
    constexpr int NT = K / 32;  // 16

    int wg = blockIdx.x;             // 0..2047
    int bz = wg & 7;                 // XCD i <-> batch i
    int by = (wg >> 3) & 15;
    int bx = wg >> 7;

    const unsigned short* Ab = A + ((size_t)bz * DKDIM + by * 128) * K;
    const unsigned short* Bb = B + ((size_t)bz * DKDIM + bx * 128) * K;

    __shared__ unsigned short lds[2][8192];   // [buf][A 4096 | B 4096] elems

    int t = threadIdx.x;             // 0..255
    int w = t >> 6, l = t & 63;
    int wm = w >> 1, wn = w & 1;     // 2M x 2N
    int lm = l & 15, lg = l >> 4;

    // staging: thread t -> row rs (0..31 | 64..95) + h*32, phys chunk t&3
    int rs = ((t >> 2) & 31) + ((t >> 7) << 6);
    int cs = (t & 3) ^ ((t >> 3) & 3);           // pre-swizzled source chunk
    const unsigned short* pAs = Ab + (size_t)rs * K + cs * 8;
    const unsigned short* pBs = Bb + (size_t)rs * K + cs * 8;
    int dstoff = ((t >> 2) & 31) * 32 + ((t >> 7) << 11) + (t & 3) * 8;  // +h*1024

    // ds_read byte offsets; (arow>>1)&3 == (lm>>1)&3
    int aoff[4], boff[4];
    #pragma unroll
    for (int f = 0; f < 4; ++f) {
        int arow = wm * 64 + f * 16 + lm;
        aoff[f] = (arow * 32 + ((lg ^ ((lm >> 1) & 3)) << 3)) * 2;
        int brow = wn * 64 + f * 16 + lm;
        boff[f] = (4096 + brow * 32 + ((lg ^ ((lm >> 1) & 3)) << 3)) * 2;
    }

#define LD_A1(buf, f) \
    (*reinterpret_cast<const bf16x8*>((const char*)(&lds[buf][0]) + aoff[f]))
#define LD_B1(buf, f) \
    (*reinterpret_cast<const bf16x8*>((const char*)(&lds[buf][0]) + boff[f]))
#define STAGE_A1(buf, h, tt) \
    gload_lds16(pAs + (size_t)((h) * 32) * K + (tt) * 32, &lds[buf][dstoff + (h) * 1024])
#define STAGE_B1(buf, h, tt) \
    gload_lds16(pBs + (size_t)((h) * 32) * K + (tt) * 32, &lds[buf][4096 + dstoff + (h) * 1024])

    f32x4 acc[4][4] = {};
    bf16x8 alo[2], ahi[2], blo[2], bhi[2];

    // prologue: t0 {Alo,Blo,Bhi,Ahi} + t1 {Alo,Blo}; vmcnt(2) => t0 landed
    STAGE_A1(0, 0, 0); STAGE_B1(0, 0, 0); STAGE_B1(0, 1, 0); STAGE_A1(0, 1, 0);
    STAGE_A1(1, 0, 1); STAGE_B1(1, 0, 1);
    asm volatile("s_waitcnt vmcnt(2)" ::: "memory");
    PH_BARRIER();

#define MFMA_Q1(AF, BF, MO, NO)                                                 \
    _Pragma("unroll") for (int mf = 0; mf < 2; ++mf)                            \
    _Pragma("unroll") for (int nf = 0; nf < 2; ++nf)                            \
        acc[(MO) + mf][(NO) + nf] = __builtin_amdgcn_mfma_f32_16x16x32_bf16(    \
            BF[nf], AF[mf], acc[(MO) + mf][(NO) + nf], 0, 0, 0);

    #pragma unroll 2
    for (int tt = 0; tt < NT; ++tt) {
        int buf = tt & 1;
        // ---- phA: q00 + q01 ; stage Ahi,Bhi(t+1) -> buf^1 ----
        #pragma unroll
        for (int f = 0; f < 2; ++f) {
            alo[f] = LD_A1(buf, f);
            blo[f] = LD_B1(buf, f);
            bhi[f] = LD_B1(buf, f + 2);
        }
        if (tt + 1 < NT) {
            STAGE_A1(buf ^ 1, 1, tt + 1);
            STAGE_B1(buf ^ 1, 1, tt + 1);
        }
        PH_BARRIER();
        asm volatile("s_waitcnt lgkmcnt(0)" ::: "memory");
        __builtin_amdgcn_sched_barrier(0);
        __builtin_amdgcn_s_setprio(1);
        MFMA_Q1(alo, blo, 0, 0)
        MFMA_Q1(alo, bhi, 0, 2)
        __builtin_amdgcn_s_setprio(0);
        PH_BARRIER();
        // ---- phB: q11 + q10 ; stage Alo,Blo(t+2) -> buf ; vmcnt ----
        #pragma unroll
        for (int f = 0; f < 2; ++f) ahi[f] = LD_A1(buf, f + 2);
        if (tt + 2 < NT) {
            STAGE_A1(buf, 0, tt + 2);
            STAGE_B1(buf, 0, tt + 2);
        }
        PH_BARRIER();
        asm volatile("s_waitcnt lgkmcnt(0)" ::: "memory");
        __builtin_amdgcn_sched_barrier(0);
        __builtin_amdgcn_s_setprio(1);
        MFMA_Q1(ahi, bhi, 2, 2)
        MFMA_Q1(ahi, blo, 2, 0)
        __builtin_amdgcn_s_setprio(0);
        if (tt < NT - 2) {
            asm volatile("s_waitcnt vmcnt(2)" ::: "memory");
        } else if (tt == NT - 2) {
            asm volatile("s_waitcnt vmcnt(0)" ::: "memory");
        }
        PH_BARRIER();
    }
#undef MFMA_Q1
#undef LD_A1
#undef LD_B1
#undef STAGE_A1
#undef STAGE_B1

    // ---- epilogue: exp, packed bf16 store, butterfly column sums ----
    unsigned short* Eb = E + (size_t)bz * DKDIM * DKDIM;
    int nbase = bx * 128 + wn * 64 + lg * 4;
    float csum[16];
    #pragma unroll
    for (int x = 0; x < 16; ++x) csum[x] = 0.f;
    #pragma unroll
    for (int mf = 0; mf < 4; ++mf) {
        int row = by * 128 + wm * 64 + mf * 16 + lm;
        #pragma unroll
        for (int nf = 0; nf < 4; ++nf) {
            f32x4 a = acc[mf][nf];
            float e0 = __expf(scale * a[0]);
            float e1 = __expf(scale * a[1]);
            float e2 = __expf(scale * a[2]);
            float e3 = __expf(scale * a[3]);
            csum[nf * 4 + 0] += e0;
            csum[nf * 4 + 1] += e1;
            csum[nf * 4 + 2] += e2;
            csum[nf * 4 + 3] += e3;
            ushort4 o;
            o.x = f2bf(e0); o.y = f2bf(e1); o.z = f2bf(e2); o.w = f2bf(e3);
            *reinterpret_cast<ushort4*>(&Eb[(size_t)row * N + nbase + nf * 16]) = o;
        }
    }
    // transposing butterfly over the 16 lm-lanes (verified r10)
    float c8[8], c4[4], c2[2], val;
    {
        bool s0 = (lm & 1);
        #pragma unroll
        for (int i = 0; i < 8; ++i) {
            float keep = s0 ? csum[2 * i + 1] : csum[2 * i];
            float send = s0 ? csum[2 * i]     : csum[2 * i + 1];
            c8[i] = keep + __shfl_xor(send, 1, 64);
        }
        bool s1 = (lm & 2);
        #pragma unroll
        for (int i = 0; i < 4; ++i) {
            float keep = s1 ? c8[2 * i + 1] : c8[2 * i];
            float send = s1 ? c8[2 * i]     : c8[2 * i + 1];
            c4[i] = keep + __shfl_xor(send, 2, 64);
        }
        bool s2 = (lm & 4);
        #pragma unroll
        for (int i = 0; i < 2; ++i) {
            float keep = s2 ? c4[2 * i + 1] : c4[2 * i];
            float send = s2 ? c4[2 * i]     : c4[2 * i + 1];
            c2[i] = keep + __shfl_xor(send, 4, 64);
        }
        bool s3 = (lm & 8);
        float keep = s3 ? c2[1] : c2[0];
        float send = s3 ? c2[0] : c2[1];
        val = keep + __shfl_xor(send, 8, 64);
    }
    int e = bx * 128 + wn * 64 + (lm >> 2) * 16 + lg * 4 + (lm & 3);
    rpart[((size_t)(by * 2 + wm) * BS + bz) * (size_t)DKDIM + e] = val;
}

// ---------------------------------------------------------------------------
// GEMM2: out = vp * E^T. BM=256 x BN=128, BK=64, NT=32, 8 waves (4Mx2N),
// 4 quadrant phases of 8 MFMA, counted vmcnt(5), XCD-swizzled 1D grid.
// Byte-identical to r8/r9/r10 (verified).
// ---------------------------------------------------------------------------
__global__ __launch_bounds__(512, 2) void gemm2_av_pipe(
    const unsigned short* __restrict__ A,   // vp [b][512][2048]
    const unsigned short* __restrict__ B,   // E  [b][2048][2048]
    float* __restrict__ C)                  // out [b][512][2048]
{
    constexpr int K = DKDIM;    // 2048
    constexpr int N = DKDIM;
    constexpr int NT = K / 64;  // 32

    int wg = blockIdx.x;                    // 0..255
    int swz = (wg & 7) * 32 + (wg >> 3);    // bijective, 256 = 8*32
    int bz = swz >> 5, rem = swz & 31, by = rem >> 4, bx = rem & 15;

    const unsigned short* Ab = A + ((size_t)bz * SEQ + by * 256) * K;
    const unsigned short* Bb = B + ((size_t)bz * DKDIM + bx * 128) * K;

    __shared__ unsigned short lds[2][256 * 64 + 128 * 64];   // A then B

    int t = threadIdx.x;
    int w = t >> 6, l = t & 63;
    int wm = w >> 1, wn = w & 1;     // 4M x 2N
    int lm = l & 15, lg = l >> 4;

    int srow = t >> 3;
    int schunk = (t & 7) ^ (srow & 7);

    int rA = (srow & 31) + ((t >> 8) << 6);
    const unsigned short* pA = Ab + (size_t)rA * K + schunk * 8;
    const unsigned short* pB = Bb + (size_t)rA * K + schunk * 8;

    int aoff[4][2], boff[4][2];
    #pragma unroll
    for (int mf = 0; mf < 4; ++mf)
        #pragma unroll
        for (int ks = 0; ks < 2; ++ks) {
            int arow = wm * 64 + mf * 16 + lm;
            int kc = ks * 4 + lg;
            aoff[mf][ks] = (arow * 64 + ((kc ^ (arow & 7)) << 3)) * 2;
            int brow = wn * 64 + mf * 16 + lm;
            boff[mf][ks] = (16384 + brow * 64 + ((kc ^ (brow & 7)) << 3)) * 2;
        }

#define LD_A2(buf, mf, ks) \
    (*reinterpret_cast<const bf16x8*>((const char*)(&lds[buf][0]) + aoff[mf][ks]))
#define LD_B2(buf, nf, ks) \
    (*reinterpret_cast<const bf16x8*>((const char*)(&lds[buf][0]) + boff[nf][ks]))
#define STAGE_A2(buf, hi, tt) do {                                             \
        const unsigned short* g = pA + (hi) * 32 * K + (tt) * 64;              \
        unsigned short* d = &lds[buf][(hi) * 2048 + ((t >> 8) << 12) + (t & 255) * 8]; \
        gload_lds16(g, d);                                                     \
        gload_lds16(g + (size_t)128 * K, d + 8192);                            \
    } while (0)
#define STAGE_B2(buf, hi, tt) do {                                             \
        const unsigned short* g = pB + (hi) * 32 * K + (tt) * 64;              \
        unsigned short* d = &lds[buf][16384 + (hi) * 2048 + ((t >> 8) << 12) + (t & 255) * 8]; \
        gload_lds16(g, d);                                                     \
    } while (0)

    f32x4 acc[4][4] = {};
    bf16x8 alo[2][2], ahi[2][2], blo[2][2], bhi[2][2];

    STAGE_A2(0, 0, 0); STAGE_A2(0, 1, 0); STAGE_B2(0, 0, 0); STAGE_B2(0, 1, 0);
    STAGE_A2(1, 0, 1); STAGE_B2(1, 0, 1); STAGE_A2(1, 1, 1);
    asm volatile("s_waitcnt vmcnt(5)" ::: "memory");
    PH_BARRIER();

#define MFMA_Q2(AF, BF, MO, NO)                                                 \
    _Pragma("unroll") for (int ks = 0; ks < 2; ++ks)                            \
    _Pragma("unroll") for (int mf = 0; mf < 2; ++mf)                            \
    _Pragma("unroll") for (int nf = 0; nf < 2; ++nf)                            \
        acc[(MO) + mf][(NO) + nf] = __builtin_amdgcn_mfma_f32_16x16x32_bf16(    \
            BF[ks][nf], AF[ks][mf], acc[(MO) + mf][(NO) + nf], 0, 0, 0);

    #pragma unroll 2
    for (int tt = 0; tt < NT; ++tt) {
        int buf = tt & 1;
        // ---- ph0: alo x blo ----
        #pragma unroll
        for (int ks = 0; ks < 2; ++ks)
            #pragma unroll
            for (int f = 0; f < 2; ++f) {
                alo[ks][f] = LD_A2(buf, f, ks);
                blo[ks][f] = LD_B2(buf, f, ks);
            }
        if (tt + 1 < NT) STAGE_B2(buf ^ 1, 1, tt + 1);
        PH_BARRIER();
        asm volatile("s_waitcnt lgkmcnt(0)" ::: "memory");
        __builtin_amdgcn_sched_barrier(0);
        __builtin_amdgcn_s_setprio(1);
        MFMA_Q2(alo, blo, 0, 0)
        __builtin_amdgcn_s_setprio(0);
        PH_BARRIER();
        // ---- ph1: alo x bhi ----
        #pragma unroll
        for (int ks = 0; ks < 2; ++ks)
            #pragma unroll
            for (int f = 0; f < 2; ++f) bhi[ks][f] = LD_B2(buf, f + 2, ks);
        if (tt + 2 < NT) STAGE_A2(buf, 0, tt + 2);
        PH_BARRIER();
        asm volatile("s_waitcnt lgkmcnt(0)" ::: "memory");
        __builtin_amdgcn_sched_barrier(0);
        __builtin_amdgcn_s_setprio(1);
        MFMA_Q2(alo, bhi, 0, 2)
        __builtin_amdgcn_s_setprio(0);
        PH_BARRIER();
        // ---- ph2: ahi x bhi ----
        #pragma unroll
        for (int ks = 0; ks < 2; ++ks)
            #pragma unroll
            for (int f = 0; f < 2; ++f) ahi[ks][f] = LD_A2(buf, f + 2, ks);
        if (tt + 2 < NT) STAGE_B2(buf, 0, tt + 2);
        PH_BARRIER();
        asm volatile("s_waitcnt lgkmcnt(0)" ::: "memory");
        __builtin_amdgcn_sched_barrier(0);
        __builtin_amdgcn_s_setprio(1);
        MFMA_Q2(ahi, bhi, 2, 2)
        __builtin_amdgcn_s_setprio(0);
        PH_BARRIER();
        // ---- ph3: ahi x blo (regs held) ----
        if (tt + 2 < NT) STAGE_A2(buf, 1, tt + 2);
        PH_BARRIER();
        __builtin_amdgcn_s_setprio(1);
        MFMA_Q2(ahi, blo, 2, 0)
        __builtin_amdgcn_s_setprio(0);
        if (tt < NT - 2) {
            asm volatile("s_waitcnt vmcnt(5)" ::: "memory");
        } else if (tt == NT - 2) {
            asm volatile("s_waitcnt vmcnt(0)" ::: "memory");
        }
        PH_BARRIER();
    }
#undef MFMA_Q2
#undef LD_A2
#undef LD_B2
#undef STAGE_A2
#undef STAGE_B2

    float* Cf = C + (size_t)bz * SEQ * DKDIM;
    int mbase = by * 256 + wm * 64 + lm;
    int nbase = bx * 128 + wn * 64 + lg * 4;
    #pragma unroll
    for (int i = 0; i < 4; ++i)
        #pragma unroll
        for (int j = 0; j < 4; ++j)
            *reinterpret_cast<f32x4*>(&Cf[(size_t)(mbase + i * 16) * N + nbase + j * 16]) = acc[i][j];
}

// ---------------------------------------------------------------------------
// rinv[b][e] = 1 / sum over 32 partials
// ---------------------------------------------------------------------------
__global__ __launch_bounds__(256) void colsum_finish(
    const float* __restrict__ rpart, float* __restrict__ rinv)
{
    int i = blockIdx.x * 256 + threadIdx.x;
    float s = 0.f;
    #pragma unroll
    for (int p = 0; p < 32; ++p) s += rpart[(size_t)p * BS * DKDIM + i];
    rinv[i] = 1.0f / s;
}

// ---------------------------------------------------------------------------
// v'[b][s][e] = bf16( v[b][s][e] * rinv[b][e] )
// ---------------------------------------------------------------------------
__global__ __launch_bounds__(256) void vprime_kernel(
    const float* __restrict__ v, const float* __restrict__ rinv,
    unsigned short* __restrict__ vp)
{
    size_t i4 = ((size_t)blockIdx.x * 256 + threadIdx.x) * 4;
    int e = (int)(i4 & (DKDIM - 1));
    int b = (int)(i4 >> 20);
    float4 v4 = *reinterpret_cast<const float4*>(&v[i4]);
    float4 r4 = *reinterpret_cast<const float4*>(&rinv[(size_t)b * DKDIM + e]);
    ushort4 o;
    o.x = f2bf(v4.x * r4.x);
    o.y = f2bf(v4.y * r4.y);
    o.z = f2bf(v4.z * r4.z);
    o.w = f2bf(v4.w * r4.w);
    *reinterpret_cast<ushort4*>(&vp[i4]) = o;
}

extern "C" void kernel_launch(void* const* d_in, const int* in_sizes, int n_in,
                              void* d_out, int out_size, void* d_ws, size_t ws_size,
                              hipStream_t stream) {
    const float* q = (const float*)d_in[0];
    const float* k = (const float*)d_in[1];
    const float* v = (const float*)d_in[2];
    float* out = (float*)d_out;

    char* ws = (char*)d_ws;
    unsigned short* qT = (unsigned short*)(ws);                        // 16 MB
    unsigned short* kT = (unsigned short*)(ws + 16777216);             // 16 MB
    unsigned short* E  = (unsigned short*)(ws + 33554432);             // 64 MB
    float* rpart       = (float*)(ws + 100663296);                     // 2 MB (32x8x2048 f32)
    float* rinv        = (float*)(ws + 102760448);                     // 64 KB
    unsigned short* vp = (unsigned short*)(ws + 103809024);            // 16 MB

    const float scale = 0.022097086912079608f;  // 1/sqrt(2048)

    transpose_conv_kernel<<<dim3(DKDIM / 64, SEQ / 64, 2 * BS), 256, 0, stream>>>(q, k, qT, kT);

    gemm1_qk_exp<<<dim3(2048), 256, 0, stream>>>(qT, kT, E, rpart, scale);

    colsum_finish<<<dim3(BS * DKDIM / 256), 256, 0, stream>>>(rpart, rinv);

    vprime_kernel<<<dim3(BS * SEQ * DKDIM / 1024), 256, 0, stream>>>(v, rinv, vp);

    gemm2_av_pipe<<<dim3(256), 512, 0, stream>>>(vp, E, out);
}

// Round 13
// 116.385 us; speedup vs baseline: 1.0338x; 1.0338x over previous
//
#include <hip/hip_runtime.h>
#include <hip/hip_bf16.h>

#define BS 8
#define SEQ 512
#define DKDIM 2048

using bf16x8 = __attribute__((ext_vector_type(8))) __bf16;
using f32x4  = __attribute__((ext_vector_type(4))) float;

__device__ __forceinline__ unsigned short f2bf(float f) {
    unsigned int u = __builtin_bit_cast(unsigned int, f);
    u += 0x7FFFu + ((u >> 16) & 1u);
    return (unsigned short)(u >> 16);
}

__device__ __forceinline__ void gload_lds16(const unsigned short* g, unsigned short* l) {
    __builtin_amdgcn_global_load_lds(
        (const __attribute__((address_space(1))) unsigned int*)g,
        (__attribute__((address_space(3))) unsigned int*)l, 16, 0, 0);
}

#define PH_BARRIER() asm volatile("s_barrier" ::: "memory")

// ---------------------------------------------------------------------------
// Transpose+convert: in [SEQ][DK] f32 (per batch) -> out [DK][SEQ] bf16
// ---------------------------------------------------------------------------
__global__ __launch_bounds__(256) void transpose_conv_kernel(
    const float* __restrict__ q, const float* __restrict__ k,
    unsigned short* __restrict__ qT, unsigned short* __restrict__ kT)
{
    int z = blockIdx.z;
    const float* in = (z < BS) ? q : k;
    unsigned short* out = (z < BS) ? qT : kT;
    int b = z & (BS - 1);
    in  += (size_t)b * SEQ * DKDIM;
    out += (size_t)b * DKDIM * SEQ;
    int s0 = blockIdx.y * 64;
    int d0 = blockIdx.x * 64;
    __shared__ unsigned short tile[64][66];
    int t = threadIdx.x;
    int tr  = t >> 4;
    int tc4 = (t & 15) * 4;
    #pragma unroll
    for (int p = 0; p < 4; ++p) {
        int s = p * 16 + tr;
        float4 v4 = *reinterpret_cast<const float4*>(&in[(size_t)(s0 + s) * DKDIM + d0 + tc4]);
        tile[s][tc4 + 0] = f2bf(v4.x);
        tile[s][tc4 + 1] = f2bf(v4.y);
        tile[s][tc4 + 2] = f2bf(v4.z);
        tile[s][tc4 + 3] = f2bf(v4.w);
    }
    __syncthreads();
    #pragma unroll
    for (int p = 0; p < 4; ++p) {
        int d = p * 16 + tr;
        ushort4 o;
        o.x = tile[tc4 + 0][d];
        o.y = tile[tc4 + 1][d];
        o.z = tile[tc4 + 2][d];
        o.w = tile[tc4 + 3][d];
        *reinterpret_cast<ushort4*>(&out[(size_t)(d0 + d) * SEQ + s0 + tc4]) = o;
    }
}

// ---------------------------------------------------------------------------
// GEMM1 (TRIPLE-BUFFER, 1 barrier/k-tile): E = exp(scale*(qT kT^T)) + partials.
// BM=BN=128, BK=32, NT=16, 4 waves (2Mx2N), wave tile 64x64, acc[4][4].
// LDS = 3 bufs x 16KB = 48KB; launch_bounds(256,3) => 3 blocks/CU.
// r12's schedule (liveness proof in r12 comments holds) with the r12 BUG
// FIXED: MFMA operand fragment index is (MO)+mf / (NO)+nf (acc index ==
// fragment index; r12's /2 variant fed q01/q11/q10 the wrong fragments).
// Per-tile: {rd 8 b128 from buf[t%3]; issue 4 gloads(t+2)->buf[(t+2)%3];
// lgkm0; 16 MFMA; vmcnt(4); BAR}.  vmcnt(0) at NT-2; no barrier after NT-1.
// Swizzle (r11-verified, 0 conflicts): chunk ^= (row>>1)&3 both sides.
// Grid 2048, bz=wg&7 => XCD i owns batch i.
// ---------------------------------------------------------------------------
__global__ __launch_bounds__(256, 3) void gemm1_qk_exp(
    const unsigned short* __restrict__ A,   // qT [b][2048][512]
    const unsigned short* __restrict__ B,   // kT [b][2048][512]
    unsigned short* __restrict__ E,         // [b][2048][2048]
    float* __restrict__ rpart,              // [32][BS][2048]
    float scale)
{
    constexpr int K = SEQ;      // 512
    constexpr int N = DKDIM;    // 2048
    constexpr int NT = K / 32;  // 16

    int wg = blockIdx.x;             // 0..2047
    int bz = wg & 7;                 // XCD i <-> batch i
    int by = (wg >> 3) & 15;
    int bx = wg >> 7;

    const unsigned short* Ab = A + ((size_t)bz * DKDIM + by * 128) * K;
    const unsigned short* Bb = B + ((size_t)bz * DKDIM + bx * 128) * K;

    __shared__ unsigned short lds[3][8192];   // [buf][A 4096 | B 4096] elems

    int t = threadIdx.x;             // 0..255
    int w = t >> 6, l = t & 63;
    int wm = w >> 1, wn = w & 1;     // 2M x 2N
    int lm = l & 15, lg = l >> 4;

    // staging: thread t -> row rs (0..31 | 64..95) + h*32, phys chunk t&3
    int rs = ((t >> 2) & 31) + ((t >> 7) << 6);
    int cs = (t & 3) ^ ((t >> 3) & 3);           // pre-swizzled source chunk
    const unsigned short* pAs = Ab + (size_t)rs * K + cs * 8;
    const unsigned short* pBs = Bb + (size_t)rs * K + cs * 8;
    int dstoff = ((t >> 2) & 31) * 32 + ((t >> 7) << 11) + (t & 3) * 8;  // +h*1024

    // ds_read byte offsets; (arow>>1)&3 == (lm>>1)&3
    int aoff[4], boff[4];
    #pragma unroll
    for (int f = 0; f < 4; ++f) {
        int arow = wm * 64 + f * 16 + lm;
        aoff[f] = (arow * 32 + ((lg ^ ((lm >> 1) & 3)) << 3)) * 2;
        int brow = wn * 64 + f * 16 + lm;
        boff[f] = (4096 + brow * 32 + ((lg ^ ((lm >> 1) & 3)) << 3)) * 2;
    }

#define LD_A1(buf, f) \
    (*reinterpret_cast<const bf16x8*>((const char*)(&lds[buf][0]) + aoff[f]))
#define LD_B1(buf, f) \
    (*reinterpret_cast<const bf16x8*>((const char*)(&lds[buf][0]) + boff[f]))
#define STAGE_A1(buf, h, tt) \
    gload_lds16(pAs + (size_t)((h) * 32) * K + (tt) * 32, &lds[buf][dstoff + (h) * 1024])
#define STAGE_B1(buf, h, tt) \
    gload_lds16(pBs + (size_t)((h) * 32) * K + (tt) * 32, &lds[buf][4096 + dstoff + (h) * 1024])

    f32x4 acc[4][4] = {};
    bf16x8 af[4], bf[4];

    // prologue: tile0 (4 calls) + tile1 (4 calls); vmcnt(4) => t0 landed
    STAGE_A1(0, 0, 0); STAGE_A1(0, 1, 0); STAGE_B1(0, 0, 0); STAGE_B1(0, 1, 0);
    STAGE_A1(1, 0, 1); STAGE_A1(1, 1, 1); STAGE_B1(1, 0, 1); STAGE_B1(1, 1, 1);
    asm volatile("s_waitcnt vmcnt(4)" ::: "memory");
    PH_BARRIER();

// fragment index == acc index (FIX of r12: no /2)
#define MFMA_Q1(AF, BF, MO, NO)                                                 \
    _Pragma("unroll") for (int mf = 0; mf < 2; ++mf)                            \
    _Pragma("unroll") for (int nf = 0; nf < 2; ++nf)                            \
        acc[(MO) + mf][(NO) + nf] = __builtin_amdgcn_mfma_f32_16x16x32_bf16(    \
            BF[(NO) + nf], AF[(MO) + mf], acc[(MO) + mf][(NO) + nf], 0, 0, 0);

    #pragma unroll
    for (int tt = 0; tt < NT; ++tt) {
        int buf = tt % 3;
        int nbuf = (tt + 2) % 3;
        // ---- reads (8 b128) ----
        #pragma unroll
        for (int f = 0; f < 4; ++f) {
            af[f] = LD_A1(buf, f);
            bf[f] = LD_B1(buf, f);
        }
        // ---- stage t+2 (4 gloads) ----
        if (tt + 2 < NT) {
            STAGE_A1(nbuf, 0, tt + 2);
            STAGE_A1(nbuf, 1, tt + 2);
            STAGE_B1(nbuf, 0, tt + 2);
            STAGE_B1(nbuf, 1, tt + 2);
        }
        // ---- compute (16 MFMA) ----
        asm volatile("s_waitcnt lgkmcnt(0)" ::: "memory");
        __builtin_amdgcn_sched_barrier(0);
        __builtin_amdgcn_s_setprio(1);
        MFMA_Q1(af, bf, 0, 0)
        MFMA_Q1(af, bf, 0, 2)
        MFMA_Q1(af, bf, 2, 2)
        MFMA_Q1(af, bf, 2, 0)
        __builtin_amdgcn_s_setprio(0);
        // ---- tile-end wait + single barrier ----
        if (tt < NT - 2) {
            asm volatile("s_waitcnt vmcnt(4)" ::: "memory");
            PH_BARRIER();
        } else if (tt == NT - 2) {
            asm volatile("s_waitcnt vmcnt(0)" ::: "memory");
            PH_BARRIER();
        }
        // tt == NT-1: no barrier needed (epilogue is register-only)
    }
#undef MFMA_Q1
#undef LD_A1
#undef LD_B1
#undef STAGE_A1
#undef STAGE_B1

    // ---- epilogue: exp, packed bf16 store, butterfly column sums ----
    unsigned short* Eb = E + (size_t)bz * DKDIM * DKDIM;
    int nbase = bx * 128 + wn * 64 + lg * 4;
    float csum[16];
    #pragma unroll
    for (int x = 0; x < 16; ++x) csum[x] = 0.f;
    #pragma unroll
    for (int mf = 0; mf < 4; ++mf) {
        int row = by * 128 + wm * 64 + mf * 16 + lm;
        #pragma unroll
        for (int nf = 0; nf < 4; ++nf) {
            f32x4 a = acc[mf][nf];
            float e0 = __expf(scale * a[0]);
            float e1 = __expf(scale * a[1]);
            float e2 = __expf(scale * a[2]);
            float e3 = __expf(scale * a[3]);
            csum[nf * 4 + 0] += e0;
            csum[nf * 4 + 1] += e1;
            csum[nf * 4 + 2] += e2;
            csum[nf * 4 + 3] += e3;
            ushort4 o;
            o.x = f2bf(e0); o.y = f2bf(e1); o.z = f2bf(e2); o.w = f2bf(e3);
            *reinterpret_cast<ushort4*>(&Eb[(size_t)row * N + nbase + nf * 16]) = o;
        }
    }
    // transposing butterfly over the 16 lm-lanes (verified r10/r11)
    float c8[8], c4[4], c2[2], val;
    {
        bool s0 = (lm & 1);
        #pragma unroll
        for (int i = 0; i < 8; ++i) {
            float keep = s0 ? csum[2 * i + 1] : csum[2 * i];
            float send = s0 ? csum[2 * i]     : csum[2 * i + 1];
            c8[i] = keep + __shfl_xor(send, 1, 64);
        }
        bool s1 = (lm & 2);
        #pragma unroll
        for (int i = 0; i < 4; ++i) {
            float keep = s1 ? c8[2 * i + 1] : c8[2 * i];
            float send = s1 ? c8[2 * i]     : c8[2 * i + 1];
            c4[i] = keep + __shfl_xor(send, 2, 64);
        }
        bool s2 = (lm & 4);
        #pragma unroll
        for (int i = 0; i < 2; ++i) {
            float keep = s2 ? c4[2 * i + 1] : c4[2 * i];
            float send = s2 ? c4[2 * i]     : c4[2 * i + 1];
            c2[i] = keep + __shfl_xor(send, 4, 64);
        }
        bool s3 = (lm & 8);
        float keep = s3 ? c2[1] : c2[0];
        float send = s3 ? c2[0] : c2[1];
        val = keep + __shfl_xor(send, 8, 64);
    }
    int e = bx * 128 + wn * 64 + (lm >> 2) * 16 + lg * 4 + (lm & 3);
    rpart[((size_t)(by * 2 + wm) * BS + bz) * (size_t)DKDIM + e] = val;
}

// ---------------------------------------------------------------------------
// GEMM2: out = vp * E^T. BM=256 x BN=128, BK=64, NT=32, 8 waves (4Mx2N),
// 4 quadrant phases of 8 MFMA, counted vmcnt(5), XCD-swizzled 1D grid.
// Byte-identical to r8-r11 (verified).
// ---------------------------------------------------------------------------
__global__ __launch_bounds__(512, 2) void gemm2_av_pipe(
    const unsigned short* __restrict__ A,   // vp [b][512][2048]
    const unsigned short* __restrict__ B,   // E  [b][2048][2048]
    float* __restrict__ C)                  // out [b][512][2048]
{
    constexpr int K = DKDIM;    // 2048
    constexpr int N = DKDIM;
    constexpr int NT = K / 64;  // 32

    int wg = blockIdx.x;                    // 0..255
    int swz = (wg & 7) * 32 + (wg >> 3);    // bijective, 256 = 8*32
    int bz = swz >> 5, rem = swz & 31, by = rem >> 4, bx = rem & 15;

    const unsigned short* Ab = A + ((size_t)bz * SEQ + by * 256) * K;
    const unsigned short* Bb = B + ((size_t)bz * DKDIM + bx * 128) * K;

    __shared__ unsigned short lds[2][256 * 64 + 128 * 64];   // A then B

    int t = threadIdx.x;
    int w = t >> 6, l = t & 63;
    int wm = w >> 1, wn = w & 1;     // 4M x 2N
    int lm = l & 15, lg = l >> 4;

    int srow = t >> 3;
    int schunk = (t & 7) ^ (srow & 7);

    int rA = (srow & 31) + ((t >> 8) << 6);
    const unsigned short* pA = Ab + (size_t)rA * K + schunk * 8;
    const unsigned short* pB = Bb + (size_t)rA * K + schunk * 8;

    int aoff[4][2], boff[4][2];
    #pragma unroll
    for (int mf = 0; mf < 4; ++mf)
        #pragma unroll
        for (int ks = 0; ks < 2; ++ks) {
            int arow = wm * 64 + mf * 16 + lm;
            int kc = ks * 4 + lg;
            aoff[mf][ks] = (arow * 64 + ((kc ^ (arow & 7)) << 3)) * 2;
            int brow = wn * 64 + mf * 16 + lm;
            boff[mf][ks] = (16384 + brow * 64 + ((kc ^ (brow & 7)) << 3)) * 2;
        }

#define LD_A2(buf, mf, ks) \
    (*reinterpret_cast<const bf16x8*>((const char*)(&lds[buf][0]) + aoff[mf][ks]))
#define LD_B2(buf, nf, ks) \
    (*reinterpret_cast<const bf16x8*>((const char*)(&lds[buf][0]) + boff[nf][ks]))
#define STAGE_A2(buf, hi, tt) do {                                             \
        const unsigned short* g = pA + (hi) * 32 * K + (tt) * 64;              \
        unsigned short* d = &lds[buf][(hi) * 2048 + ((t >> 8) << 12) + (t & 255) * 8]; \
        gload_lds16(g, d);                                                     \
        gload_lds16(g + (size_t)128 * K, d + 8192);                            \
    } while (0)
#define STAGE_B2(buf, hi, tt) do {                                             \
        const unsigned short* g = pB + (hi) * 32 * K + (tt) * 64;              \
        unsigned short* d = &lds[buf][16384 + (hi) * 2048 + ((t >> 8) << 12) + (t & 255) * 8]; \
        gload_lds16(g, d);                                                     \
    } while (0)

    f32x4 acc[4][4] = {};
    bf16x8 alo[2][2], ahi[2][2], blo[2][2], bhi[2][2];

    STAGE_A2(0, 0, 0); STAGE_A2(0, 1, 0); STAGE_B2(0, 0, 0); STAGE_B2(0, 1, 0);
    STAGE_A2(1, 0, 1); STAGE_B2(1, 0, 1); STAGE_A2(1, 1, 1);
    asm volatile("s_waitcnt vmcnt(5)" ::: "memory");
    PH_BARRIER();

#define MFMA_Q2(AF, BF, MO, NO)                                                 \
    _Pragma("unroll") for (int ks = 0; ks < 2; ++ks)                            \
    _Pragma("unroll") for (int mf = 0; mf < 2; ++mf)                            \
    _Pragma("unroll") for (int nf = 0; nf < 2; ++nf)                            \
        acc[(MO) + mf][(NO) + nf] = __builtin_amdgcn_mfma_f32_16x16x32_bf16(    \
            BF[ks][nf], AF[ks][mf], acc[(MO) + mf][(NO) + nf], 0, 0, 0);

    #pragma unroll 2
    for (int tt = 0; tt < NT; ++tt) {
        int buf = tt & 1;
        // ---- ph0: alo x blo ----
        #pragma unroll
        for (int ks = 0; ks < 2; ++ks)
            #pragma unroll
            for (int f = 0; f < 2; ++f) {
                alo[ks][f] = LD_A2(buf, f, ks);
                blo[ks][f] = LD_B2(buf, f, ks);
            }
        if (tt + 1 < NT) STAGE_B2(buf ^ 1, 1, tt + 1);
        PH_BARRIER();
        asm volatile("s_waitcnt lgkmcnt(0)" ::: "memory");
        __builtin_amdgcn_sched_barrier(0);
        __builtin_amdgcn_s_setprio(1);
        MFMA_Q2(alo, blo, 0, 0)
        __builtin_amdgcn_s_setprio(0);
        PH_BARRIER();
        // ---- ph1: alo x bhi ----
        #pragma unroll
        for (int ks = 0; ks < 2; ++ks)
            #pragma unroll
            for (int f = 0; f < 2; ++f) bhi[ks][f] = LD_B2(buf, f + 2, ks);
        if (tt + 2 < NT) STAGE_A2(buf, 0, tt + 2);
        PH_BARRIER();
        asm volatile("s_waitcnt lgkmcnt(0)" ::: "memory");
        __builtin_amdgcn_sched_barrier(0);
        __builtin_amdgcn_s_setprio(1);
        MFMA_Q2(alo, bhi, 0, 2)
        __builtin_amdgcn_s_setprio(0);
        PH_BARRIER();
        // ---- ph2: ahi x bhi ----
        #pragma unroll
        for (int ks = 0; ks < 2; ++ks)
            #pragma unroll
            for (int f = 0; f < 2; ++f) ahi[ks][f] = LD_A2(buf, f + 2, ks);
        if (tt + 2 < NT) STAGE_B2(buf, 0, tt + 2);
        PH_BARRIER();
        asm volatile("s_waitcnt lgkmcnt(0)" ::: "memory");
        __builtin_amdgcn_sched_barrier(0);
        __builtin_amdgcn_s_setprio(1);
        MFMA_Q2(ahi, bhi, 2, 2)
        __builtin_amdgcn_s_setprio(0);
        PH_BARRIER();
        // ---- ph3: ahi x blo (regs held) ----
        if (tt + 2 < NT) STAGE_A2(buf, 1, tt + 2);
        PH_BARRIER();
        __builtin_amdgcn_s_setprio(1);
        MFMA_Q2(ahi, blo, 2, 0)
        __builtin_amdgcn_s_setprio(0);
        if (tt < NT - 2) {
            asm volatile("s_waitcnt vmcnt(5)" ::: "memory");
        } else if (tt == NT - 2) {
            asm volatile("s_waitcnt vmcnt(0)" ::: "memory");
        }
        PH_BARRIER();
    }
#undef MFMA_Q2
#undef LD_A2
#undef LD_B2
#undef STAGE_A2
#undef STAGE_B2

    float* Cf = C + (size_t)bz * SEQ * DKDIM;
    int mbase = by * 256 + wm * 64 + lm;
    int nbase = bx * 128 + wn * 64 + lg * 4;
    #pragma unroll
    for (int i = 0; i < 4; ++i)
        #pragma unroll
        for (int j = 0; j < 4; ++j)
            *reinterpret_cast<f32x4*>(&Cf[(size_t)(mbase + i * 16) * N + nbase + j * 16]) = acc[i][j];
}

// ---------------------------------------------------------------------------
// rinv[b][e] = 1 / sum over 32 partials
// ---------------------------------------------------------------------------
__global__ __launch_bounds__(256) void colsum_finish(
    const float* __restrict__ rpart, float* __restrict__ rinv)
{
    int i = blockIdx.x * 256 + threadIdx.x;
    float s = 0.f;
    #pragma unroll
    for (int p = 0; p < 32; ++p) s += rpart[(size_t)p * BS * DKDIM + i];
    rinv[i] = 1.0f / s;
}

// ---------------------------------------------------------------------------
// v'[b][s][e] = bf16( v[b][s][e] * rinv[b][e] )
// ---------------------------------------------------------------------------
__global__ __launch_bounds__(256) void vprime_kernel(
    const float* __restrict__ v, const float* __restrict__ rinv,
    unsigned short* __restrict__ vp)
{
    size_t i4 = ((size_t)blockIdx.x * 256 + threadIdx.x) * 4;
    int e = (int)(i4 & (DKDIM - 1));
    int b = (int)(i4 >> 20);
    float4 v4 = *reinterpret_cast<const float4*>(&v[i4]);
    float4 r4 = *reinterpret_cast<const float4*>(&rinv[(size_t)b * DKDIM + e]);
    ushort4 o;
    o.x = f2bf(v4.x * r4.x);
    o.y = f2bf(v4.y * r4.y);
    o.z = f2bf(v4.z * r4.z);
    o.w = f2bf(v4.w * r4.w);
    *reinterpret_cast<ushort4*>(&vp[i4]) = o;
}

extern "C" void kernel_launch(void* const* d_in, const int* in_sizes, int n_in,
                              void* d_out, int out_size, void* d_ws, size_t ws_size,
                              hipStream_t stream) {
    const float* q = (const float*)d_in[0];
    const float* k = (const float*)d_in[1];
    const float* v = (const float*)d_in[2];
    float* out = (float*)d_out;

    char* ws = (char*)d_ws;
    unsigned short* qT = (unsigned short*)(ws);                        // 16 MB
    unsigned short* kT = (unsigned short*)(ws + 16777216);             // 16 MB
    unsigned short* E  = (unsigned short*)(ws + 33554432);             // 64 MB
    float* rpart       = (float*)(ws + 100663296);                     // 2 MB (32x8x2048 f32)
    float* rinv        = (float*)(ws + 102760448);                     // 64 KB
    unsigned short* vp = (unsigned short*)(ws + 103809024);            // 16 MB

    const float scale = 0.022097086912079608f;  // 1/sqrt(2048)

    transpose_conv_kernel<<<dim3(DKDIM / 64, SEQ / 64, 2 * BS), 256, 0, stream>>>(q, k, qT, kT);

    gemm1_qk_exp<<<dim3(2048), 256, 0, stream>>>(qT, kT, E, rpart, scale);

    colsum_finish<<<dim3(BS * DKDIM / 256), 256, 0, stream>>>(rpart, rinv);

    vprime_kernel<<<dim3(BS * SEQ * DKDIM / 1024), 256, 0, stream>>>(v, rinv, vp);

    gemm2_av_pipe<<<dim3(256), 512, 0, stream>>>(vp, E, out);
}